// Round 7
// baseline (223.256 us; speedup 1.0000x reference)
//
#include <hip/hip_runtime.h>
#include <stdint.h>

#define B_ 2
#define S_ 2048
#define D_ 1024
#define H_ 16
#define DH_ 64
#define M_ 4096  // B_*S_

typedef unsigned short u16;
typedef unsigned int u32;
typedef short mfma_elem_t;
typedef mfma_elem_t bfrag8 __attribute__((ext_vector_type(8)));
typedef float floatx4 __attribute__((ext_vector_type(4)));
typedef float floatx16 __attribute__((ext_vector_type(16)));
typedef int intx2 __attribute__((ext_vector_type(2)));

__device__ __forceinline__ u16 f2bf(float f) {
  unsigned u = __float_as_uint(f);
  u += 0x7fff + ((u >> 16) & 1);  // RNE
  return (u16)(u >> 16);
}

// pack two positive floats to packed bf16 (round-half-up, unbiased): 3 VALU ops.
// NOTE: do NOT use v_cvt_pk_bf16_f32 here — its truncating rounding biases the
// PV numerator low by ~2^-9 rel while l stays f32 -> 1.5e-3 output error (R6).
__device__ __forceinline__ u32 pack_bf16(float a, float b) {
  u32 ua = __float_as_uint(a) + 0x8000u;
  u32 ub = __float_as_uint(b) + 0x8000u;
#if __has_builtin(__builtin_amdgcn_perm)
  return __builtin_amdgcn_perm(ub, ua, 0x07060302u);  // lo16=ua.hi, hi16=ub.hi
#else
  return (ua >> 16) | (ub & 0xffff0000u);
#endif
}

__device__ __forceinline__ void gl_lds16(const void* g, void* l) {
  __builtin_amdgcn_global_load_lds(
      (__attribute__((address_space(1))) void*)(g),
      (__attribute__((address_space(3))) void*)(l), 16, 0, 0);
}

// ---------------- convert inputs fp32 -> bf16 ----------------
__global__ __launch_bounds__(256) void k_convert_x(
    const float* __restrict__ q, const float* __restrict__ k, const float* __restrict__ v,
    u16* __restrict__ xq, u16* __restrict__ xk, u16* __restrict__ xv) {
  const float* src = blockIdx.z == 0 ? q : (blockIdx.z == 1 ? k : v);
  u16* dst = blockIdx.z == 0 ? xq : (blockIdx.z == 1 ? xk : xv);
  int i = (blockIdx.x * 256 + threadIdx.x) * 4;
  float4 f = *(const float4*)(src + i);
  ushort4 o;
  o.x = f2bf(f.x); o.y = f2bf(f.y); o.z = f2bf(f.z); o.w = f2bf(f.w);
  *(ushort4*)(dst + i) = o;
}

// ---------------- convert + transpose W fp32[1024][1024] -> bf16 W^T ----------------
__global__ __launch_bounds__(256) void k_convert_w(
    const float* __restrict__ wq, const float* __restrict__ wk,
    const float* __restrict__ wv, const float* __restrict__ wo,
    u16* __restrict__ tq, u16* __restrict__ tk, u16* __restrict__ tv, u16* __restrict__ to_) {
  const int gz = blockIdx.z;
  const float* w = gz == 0 ? wq : gz == 1 ? wk : gz == 2 ? wv : wo;
  u16* t = gz == 0 ? tq : gz == 1 ? tk : gz == 2 ? tv : to_;
  __shared__ float tile[32][33];
  int r0 = blockIdx.y * 32, c0 = blockIdx.x * 32;
  int tx = threadIdx.x, ty = threadIdx.y;
#pragma unroll
  for (int i = 0; i < 4; i++) {
    int r = ty + i * 8;
    tile[r][tx] = w[(size_t)(r0 + r) * D_ + c0 + tx];
  }
  __syncthreads();
#pragma unroll
  for (int i = 0; i < 4; i++) {
    int r = ty + i * 8;
    t[(size_t)(c0 + r) * D_ + r0 + tx] = f2bf(tile[tx][r]);
  }
}

// ---------------- fused QKV projection GEMM (dbuf, 1 barrier/iter) ----------------
// Q,K out: [B,H,S,DH]; V out: [B,H,DH,S] (transposed in epilogue)
// Q output is PRE-SCALED by log2(e)/sqrt(DH) so attention can exp2 scores directly.
__global__ __launch_bounds__(256, 3) void k_gemm_qkv(
    const u16* __restrict__ xq, const u16* __restrict__ xk, const u16* __restrict__ xv,
    const u16* __restrict__ wtq, const u16* __restrict__ wtk, const u16* __restrict__ wtv,
    const float* __restrict__ bq, const float* __restrict__ bk, const float* __restrict__ bv,
    u16* __restrict__ oq, u16* __restrict__ ok, u16* __restrict__ ovt) {
  const int gz = blockIdx.z;
  const u16* X = gz == 0 ? xq : gz == 1 ? xk : xv;
  const u16* WT = gz == 0 ? wtq : gz == 1 ? wtk : wtv;
  const float* bias = gz == 0 ? bq : gz == 1 ? bk : bv;
  u16* outsd = gz == 0 ? oq : ok;

  __shared__ u16 sbuf[2][8192];

  const int t = threadIdx.x;
  const int w = t >> 6, lane = t & 63, l15 = lane & 15, quad = lane >> 4;
  const int wm = (w >> 1) * 64, wn = (w & 1) * 64;
  const int m0 = blockIdx.y * 128, n0 = blockIdx.x * 128;

  floatx4 acc[4][4];
  floatx4 zero = {0.f, 0.f, 0.f, 0.f};
#pragma unroll
  for (int mt = 0; mt < 4; mt++)
#pragma unroll
    for (int nt = 0; nt < 4; nt++) acc[mt][nt] = zero;

  auto stage = [&](int kt, int b) {
    int k0 = kt * 32;
#pragma unroll
    for (int i = 0; i < 2; i++) {
      int chunk = i * 256 + t;
      gl_lds16(X + (size_t)(m0 + (chunk >> 2)) * D_ + k0 + (chunk & 3) * 8,
               sbuf[b] + i * 2048 + w * 512);
      gl_lds16(WT + (size_t)(n0 + (chunk >> 2)) * D_ + k0 + (chunk & 3) * 8,
               sbuf[b] + 4096 + i * 2048 + w * 512);
    }
  };

  stage(0, 0);
  for (int kt = 0; kt < 32; kt++) {
    __syncthreads();
    if (kt < 31) stage(kt + 1, (kt + 1) & 1);
    const u16* As = sbuf[kt & 1];
    const u16* Bs = sbuf[kt & 1] + 4096;
    bfrag8 af[4], bf[4];
#pragma unroll
    for (int mt = 0; mt < 4; mt++)
      af[mt] = *(const bfrag8*)(As + (wm + mt * 16 + l15) * 32 + quad * 8);
#pragma unroll
    for (int nt = 0; nt < 4; nt++)
      bf[nt] = *(const bfrag8*)(Bs + (wn + nt * 16 + l15) * 32 + quad * 8);
#pragma unroll
    for (int mt = 0; mt < 4; mt++)
#pragma unroll
      for (int nt = 0; nt < 4; nt++)
        acc[mt][nt] = __builtin_amdgcn_mfma_f32_16x16x32_bf16(af[mt], bf[nt], acc[mt][nt], 0, 0, 0);
  }

  if (gz < 2) {
    const float sc = gz == 0 ? 0.18033688011112042f : 1.0f;  // log2(e)/8 folded into Q
#pragma unroll
    for (int mt = 0; mt < 4; mt++)
#pragma unroll
      for (int nt = 0; nt < 4; nt++) {
        int Nc = n0 + wn + nt * 16 + l15;
        float bv_ = bias[Nc];
        int hh = Nc >> 6, dh = Nc & 63;
#pragma unroll
        for (int r = 0; r < 4; r++) {
          int Mr = m0 + wm + mt * 16 + quad * 4 + r;
          int bb = Mr >> 11, ss = Mr & 2047;
          outsd[((size_t)(bb * H_ + hh) * S_ + ss) * DH_ + dh] = f2bf((acc[mt][nt][r] + bv_) * sc);
        }
      }
  } else {
#pragma unroll
    for (int mt = 0; mt < 4; mt++)
#pragma unroll
      for (int nt = 0; nt < 4; nt++) {
        int Nc = n0 + wn + nt * 16 + l15;
        float bv_ = bias[Nc];
        int hh = Nc >> 6, dh = Nc & 63;
        int Mr0 = m0 + wm + mt * 16 + quad * 4;
        int bb = Mr0 >> 11, ss0 = Mr0 & 2047;
        ushort4 o;
        o.x = f2bf(acc[mt][nt][0] + bv_);
        o.y = f2bf(acc[mt][nt][1] + bv_);
        o.z = f2bf(acc[mt][nt][2] + bv_);
        o.w = f2bf(acc[mt][nt][3] + bv_);
        *(ushort4*)(ovt + ((size_t)(bb * H_ + hh) * DH_ + dh) * S_ + ss0) = o;
      }
  }
}

// ---------------- final GEMM (dbuf, 128x64 tile for 2 blocks/CU) ----------------
// out fp32 = O[4096,1024] * Wo + bo. Grid (16,32) = 512 blocks (was 256 = 1/CU).
__global__ __launch_bounds__(256, 3) void k_gemm_final(
    const u16* __restrict__ X, const u16* __restrict__ WT,
    const float* __restrict__ bias, float* __restrict__ out) {
  __shared__ u16 sbuf[2][6144];  // A [128][32] + B [64][32] per buf = 12 KB
  const int t = threadIdx.x;
  const int w = t >> 6, lane = t & 63, l15 = lane & 15, quad = lane >> 4;
  const int m0 = blockIdx.y * 128, n0 = blockIdx.x * 64;

  floatx4 acc[2][4];
  floatx4 zero = {0.f, 0.f, 0.f, 0.f};
#pragma unroll
  for (int mt = 0; mt < 2; mt++)
#pragma unroll
    for (int nt = 0; nt < 4; nt++) acc[mt][nt] = zero;

  auto stage = [&](int kt, int b) {
    int k0 = kt * 32;
    // A: 512 chunks (128 rows x 4 chunks), 2 per thread
#pragma unroll
    for (int i = 0; i < 2; i++) {
      int chunk = i * 256 + t;
      gl_lds16(X + (size_t)(m0 + (chunk >> 2)) * D_ + k0 + (chunk & 3) * 8,
               sbuf[b] + i * 2048 + w * 512);
    }
    // B: 256 chunks (64 rows x 4 chunks), 1 per thread
    {
      int chunk = t;
      gl_lds16(WT + (size_t)(n0 + (chunk >> 2)) * D_ + k0 + (chunk & 3) * 8,
               sbuf[b] + 4096 + w * 512);
    }
  };

  stage(0, 0);
  for (int kt = 0; kt < 32; kt++) {
    __syncthreads();
    if (kt < 31) stage(kt + 1, (kt + 1) & 1);
    const u16* As = sbuf[kt & 1];
    const u16* Bs = sbuf[kt & 1] + 4096;
    bfrag8 af[2], bf[4];
#pragma unroll
    for (int mt = 0; mt < 2; mt++)
      af[mt] = *(const bfrag8*)(As + (w * 32 + mt * 16 + l15) * 32 + quad * 8);
#pragma unroll
    for (int nt = 0; nt < 4; nt++)
      bf[nt] = *(const bfrag8*)(Bs + (nt * 16 + l15) * 32 + quad * 8);
#pragma unroll
    for (int mt = 0; mt < 2; mt++)
#pragma unroll
      for (int nt = 0; nt < 4; nt++)
        acc[mt][nt] = __builtin_amdgcn_mfma_f32_16x16x32_bf16(af[mt], bf[nt], acc[mt][nt], 0, 0, 0);
  }
#pragma unroll
  for (int mt = 0; mt < 2; mt++)
#pragma unroll
    for (int nt = 0; nt < 4; nt++) {
      int Nc = n0 + nt * 16 + l15;
      float bv_ = bias[Nc];
#pragma unroll
      for (int r = 0; r < 4; r++) {
        int Mr = m0 + w * 32 + mt * 16 + quad * 4 + r;
        out[(size_t)Mr * D_ + Nc] = acc[mt][nt][r] + bv_;
      }
    }
}

// ---------------- flash attention v7: 32x32 MFMA, in-reg P, lean softmax ----------------
// As v5 (256 threads, 4 waves, 32 q-rows/wave, kv-tile 64, dbuf, K/V [64][64]
// chunk-swizzled) plus: Q pre-scaled upstream (no per-score mul), s_setprio
// around MFMA clusters. P pack uses unbiased round-half-up (see pack_bf16 note).
__global__ __launch_bounds__(256, 2) void k_attn(
    const u16* __restrict__ Q, const u16* __restrict__ K,
    const u16* __restrict__ Vt, u16* __restrict__ O) {
  __shared__ u16 lds[16384];  // 32 KB: buf[2] x { K [64][64], V [64][64] }

  const int t = threadIdx.x, w = t >> 6, lane = t & 63;
  const int l31 = lane & 31, hi = lane >> 5;
  const int bh = blockIdx.z * H_ + blockIdx.y;
  const int q0 = blockIdx.x * 128;
  const u16* Qb = Q + (size_t)bh * S_ * DH_;
  const u16* Kb = K + (size_t)bh * S_ * DH_;
  const u16* Vb = Vt + (size_t)bh * DH_ * S_;

  const int xr = l31 & 7;  // read-side swizzle row bits

  // Q B-frags: lane holds Q[q=l31][dh = ks*16 + hi*8 + j], loaded once from global
  bfrag8 qf[4];
#pragma unroll
  for (int ks = 0; ks < 4; ks++)
    qf[ks] = *(const bfrag8*)(Qb + (size_t)(q0 + w * 32 + l31) * DH_ + ks * 16 + hi * 8);

  // staging: 64x64 u16 tile = 512 16B-chunks; thread t covers chunks t and 256+t.
  // phys chunk (row, cp) holds logical col cl = cp ^ (row&7) -> source col swizzled.
  const int rsub = lane >> 3;                    // row within 8-row group
  const int csw = ((lane & 7) ^ (rsub & 7)) * 8; // swizzled source col (u16 units)
  auto stage = [&](int kv0, int b) {
    u16* Kbuf = lds + b * 8192;
    u16* Vbuf = lds + b * 8192 + 4096;
#pragma unroll
    for (int i = 0; i < 2; i++) {
      int rbase = i * 32 + w * 8;
      gl_lds16(Kb + (size_t)(kv0 + rbase + rsub) * DH_ + csw,
               Kbuf + (i * 256 + w * 64) * 8);
      gl_lds16(Vb + (size_t)(rbase + rsub) * S_ + kv0 + csw,
               Vbuf + (i * 256 + w * 64) * 8);
    }
  };

  floatx16 oacc[2];
  floatx16 zero16 = {0.f, 0.f, 0.f, 0.f, 0.f, 0.f, 0.f, 0.f,
                     0.f, 0.f, 0.f, 0.f, 0.f, 0.f, 0.f, 0.f};
  oacc[0] = zero16;
  oacc[1] = zero16;
  float lrow = 0.f;  // lane-local partial (this half's kv subset); reduced at end

  stage(0, 0);
  for (int kt = 0; kt < 32; kt++) {
    __syncthreads();  // drains stage(kt); all waves done reading buf[(kt+1)&1]
    if (kt < 31) stage((kt + 1) * 64, (kt + 1) & 1);
    const u16* Kbuf = lds + (kt & 1) * 8192;
    const u16* Vbuf = lds + (kt & 1) * 8192 + 4096;

    // S^T: per mtile (kv 32-block), 4 mfma over dh. Scores already in log2 units.
    floatx16 sacc[2];
    sacc[0] = zero16;
    sacc[1] = zero16;
    __builtin_amdgcn_s_setprio(1);
#pragma unroll
    for (int mt2 = 0; mt2 < 2; mt2++)
#pragma unroll
      for (int ks = 0; ks < 4; ks++) {
        bfrag8 kf = *(const bfrag8*)(Kbuf + (mt2 * 32 + l31) * 64 + ((2 * ks + hi) ^ xr) * 8);
        sacc[mt2] = __builtin_amdgcn_mfma_f32_32x32x16_bf16(kf, qf[ks], sacc[mt2], 0, 0, 0);
      }
    __builtin_amdgcn_s_setprio(0);

    // softmax + PV, all in registers
#pragma unroll
    for (int mt2 = 0; mt2 < 2; mt2++) {
      float p[16];
      float ls = 0.f;
#pragma unroll
      for (int r = 0; r < 16; r++) {
        p[r] = __builtin_amdgcn_exp2f(sacc[mt2][r]);
        ls += p[r];
      }
      lrow += ls;
      u32 pw[8];
#pragma unroll
      for (int i = 0; i < 8; i++) pw[i] = pack_bf16(p[2 * i], p[2 * i + 1]);
#pragma unroll
      for (int st = 0; st < 2; st++) {
        intx2 sA = __builtin_amdgcn_permlane32_swap((int)pw[4 * st + 0], (int)pw[4 * st + 2], false, false);
        intx2 sB = __builtin_amdgcn_permlane32_swap((int)pw[4 * st + 1], (int)pw[4 * st + 3], false, false);
        union { u32 u[4]; bfrag8 f; } pb;
        pb.u[0] = (u32)sA[0];
        pb.u[1] = (u32)sB[0];
        pb.u[2] = (u32)sA[1];
        pb.u[3] = (u32)sB[1];
        int kvstep = mt2 * 2 + st;  // 16-kv step
        __builtin_amdgcn_s_setprio(1);
#pragma unroll
        for (int dt = 0; dt < 2; dt++) {
          bfrag8 vf = *(const bfrag8*)(Vbuf + (dt * 32 + l31) * 64 + ((2 * kvstep + hi) ^ xr) * 8);
          oacc[dt] = __builtin_amdgcn_mfma_f32_32x32x16_bf16(vf, pb.f, oacc[dt], 0, 0, 0);
        }
        __builtin_amdgcn_s_setprio(0);
      }
    }
  }

  // epilogue: combine halves' l partials, normalize, packed 8B stores
  {
    float l = lrow + __shfl_xor(lrow, 32, 64);
    float rinv = 1.0f / l;
    int qrow = q0 + w * 32 + l31;
    u16* Orow = O + ((size_t)blockIdx.z * S_ + qrow) * D_ + blockIdx.y * DH_;
#pragma unroll
    for (int dt = 0; dt < 2; dt++)
#pragma unroll
      for (int s = 0; s < 4; s++) {
        ushort4 o;
        o.x = f2bf(oacc[dt][4 * s + 0] * rinv);
        o.y = f2bf(oacc[dt][4 * s + 1] * rinv);
        o.z = f2bf(oacc[dt][4 * s + 2] * rinv);
        o.w = f2bf(oacc[dt][4 * s + 3] * rinv);
        *(ushort4*)(Orow + dt * 32 + s * 8 + hi * 4) = o;
      }
  }
}

// ---------------- launch ----------------
extern "C" void kernel_launch(void* const* d_in, const int* in_sizes, int n_in,
                              void* d_out, int out_size, void* d_ws, size_t ws_size,
                              hipStream_t stream) {
  const float* queries = (const float*)d_in[0];
  const float* keys = (const float*)d_in[1];
  const float* values = (const float*)d_in[2];
  const float* Wq = (const float*)d_in[3];
  const float* bq = (const float*)d_in[4];
  const float* Wk = (const float*)d_in[5];
  const float* bk = (const float*)d_in[6];
  const float* Wv = (const float*)d_in[7];
  const float* bv = (const float*)d_in[8];
  const float* Wo = (const float*)d_in[9];
  const float* bo = (const float*)d_in[10];

  const size_t NXB = (size_t)M_ * D_ * 2;
  const size_t WB = (size_t)D_ * D_ * 2;
  if (ws_size < 7 * NXB + 4 * WB) return;

  char* ws = (char*)d_ws;
  u16* Xq = (u16*)(ws);
  u16* Xk = (u16*)(ws + NXB);
  u16* Xv = (u16*)(ws + 2 * NXB);
  u16* WqT = (u16*)(ws + 3 * NXB);
  u16* WkT = (u16*)(ws + 3 * NXB + WB);
  u16* WvT = (u16*)(ws + 3 * NXB + 2 * WB);
  u16* WoT = (u16*)(ws + 3 * NXB + 3 * WB);
  char* ws2 = ws + 3 * NXB + 4 * WB;
  u16* Qhs = (u16*)(ws2);
  u16* Khs = (u16*)(ws2 + NXB);
  u16* VtB = (u16*)(ws2 + 2 * NXB);
  u16* Obuf = (u16*)(ws2 + 3 * NXB);
  float* outp = (float*)d_out;

  k_convert_x<<<dim3(4096, 1, 3), 256, 0, stream>>>(queries, keys, values, Xq, Xk, Xv);
  k_convert_w<<<dim3(32, 32, 4), dim3(32, 8), 0, stream>>>(Wq, Wk, Wv, Wo, WqT, WkT, WvT, WoT);
  k_gemm_qkv<<<dim3(8, 32, 3), 256, 0, stream>>>(Xq, Xk, Xv, WqT, WkT, WvT, bq, bk, bv, Qhs, Khs, VtB);
  k_attn<<<dim3(16, 16, 2), 256, 0, stream>>>(Qhs, Khs, VtB, Obuf);
  k_gemm_final<<<dim3(16, 32), 256, 0, stream>>>(Obuf, WoT, bo, outp);
}